// Round 4
// baseline (589.243 us; speedup 1.0000x reference)
//
#include <hip/hip_runtime.h>
#include <math.h>

// Quantized ConvBlock, round 4: big-tile async implicit-GEMM MFMA.
//   Pass 1: xmax.  Pass 2: xq f16 in [n][ci16][h][w][c8].  Pass 3: conv.
//   conv: A = Wq (M=o), B = xq (N=pixels).  Wave tile 128o x 128pix (1 row).
//   Block 256 thr = 4 waves (rows h0..h0+3), 128 o, full 128 w.
//   K-chunk = 8 c x 9 taps; taps paired into K=16 MFMA via q2 lane-half
//   (tap8 pads with zeroed A on q2 lanes).  [.][.][c8] LDS layout: 16 B lane
//   stride -> conflict-free b128.  Double-buffered global_load_lds staging.
//
// ws layout (bytes):
//   0       : xmax bits (uint)  [memset 0]
//   256     : fw[256] floats
//   2048    : wq_a f16 [o][tap][c]                (fallback, 589824 B)
//   655360  : wq_b f16 [ci16][oh2][tap9][o128][c8] (589824 B)
//   2097152 : xq   f16 [n][ci16][h][w][c8]        (67108864 B)

#define FW_NUM 20017.23017802413f
#define FX_NUM 835.5924988699913f
#define WQA_OFF 2048
#define WQB_OFF (640 * 1024)
#define XQ_OFF  (2 * 1024 * 1024)
#define XQ_BYTES 67108864ull

// fallback tile params (R2 kernel)
#define CK  16
#define CKP 24
#define JW  130

typedef _Float16 half8 __attribute__((ext_vector_type(8)));
typedef _Float16 half4 __attribute__((ext_vector_type(4)));
typedef float floatx16 __attribute__((ext_vector_type(16)));

__device__ __forceinline__ void gl_lds16(const void* g, void* s) {
    __builtin_amdgcn_global_load_lds((const __attribute__((address_space(1))) void*)g,
                                     (__attribute__((address_space(3))) void*)s, 16, 0, 0);
}

__global__ void xmax_kernel(const float* __restrict__ x, unsigned int* wsu, int n4) {
    int tid = blockIdx.x * blockDim.x + threadIdx.x;
    int stride = gridDim.x * blockDim.x;
    const float4* x4 = (const float4*)x;
    float m = 0.f;
    for (int i = tid; i < n4; i += stride) {
        float4 v = x4[i];
        m = fmaxf(m, fmaxf(fmaxf(fabsf(v.x), fabsf(v.y)), fmaxf(fabsf(v.z), fabsf(v.w))));
    }
    #pragma unroll
    for (int off = 32; off >= 1; off >>= 1)
        m = fmaxf(m, __shfl_down(m, off, 64));
    __shared__ float sm[4];
    if ((threadIdx.x & 63) == 0) sm[threadIdx.x >> 6] = m;
    __syncthreads();
    if (threadIdx.x == 0) {
        m = fmaxf(fmaxf(sm[0], sm[1]), fmaxf(sm[2], sm[3]));
        atomicMax(wsu, __float_as_uint(m));
    }
}

// one block per o (256 blocks, 128 threads; t = input channel c)
__global__ void wq_kernel(const float* __restrict__ W, float* wsf, int big) {
    int o = blockIdx.x;
    int t = threadIdx.x;
    const float* wrow = W + o * 1152;
    float wv[9];
    float s = 0.f;
    #pragma unroll
    for (int k = 0; k < 9; k++) { wv[k] = wrow[t * 9 + k]; s += fabsf(wv[k]); }
    #pragma unroll
    for (int off = 32; off >= 1; off >>= 1) s += __shfl_down(s, off, 64);
    __shared__ float sred[2];
    __shared__ float sfw;
    if ((t & 63) == 0) sred[t >> 6] = s;
    __syncthreads();
    if (t == 0) {
        float wsum = sred[0] + sred[1];
        if (wsum == 0.f) wsum = 1.f;
        float fw = FW_NUM / wsum;
        wsf[64 + o] = fw;
        sfw = fw;
    }
    __syncthreads();
    float fw = sfw;
    _Float16* wqa = (_Float16*)((char*)wsf + WQA_OFF);   // [o][tap][c]
    _Float16* wqb = (_Float16*)((char*)wsf + WQB_OFF);   // [ci][oh][tap][o128][c8]
    int ci = t >> 3, ce = t & 7;
    int oh = o >> 7, oi = o & 127;
    #pragma unroll
    for (int k = 0; k < 9; k++) {
        _Float16 hv = (_Float16)rintf(wv[k] * fw);       // rintf = RNE = jnp.round
        wqa[(o * 9 + k) * 128 + t] = hv;
        if (big)
            wqb[((((size_t)ci * 2 + oh) * 9 + k) * 128 + oi) * 8 + ce] = hv;
    }
}

// block = (n, ci, h): quantize 8 c-planes' row h into [w][c8]
__global__ void quantx_kernel(const float* __restrict__ x, const float* __restrict__ wsf,
                              _Float16* __restrict__ xq) {
    int bid = blockIdx.x;           // (n*16 + ci)*128 + h ; grid 32768
    int h  = bid & 127;
    int ci = (bid >> 7) & 15;
    int n  = bid >> 11;
    float xmax = __uint_as_float(((const unsigned int*)wsf)[0]);
    float fx = xmax > 0.f ? FX_NUM / xmax : 1.0f;
    int w = threadIdx.x;            // 128
    const float* xp = x + ((size_t)(n * 128 + ci * 8) * 128 + h) * 128 + w;
    half8 v;
    #pragma unroll
    for (int k = 0; k < 8; k++) v[k] = (_Float16)rintf(fx * xp[(size_t)k * 16384]);
    *(half8*)(xq + ((size_t)bid * 128 + w) * 8) = v;
}

__global__ __launch_bounds__(256, 1) void conv_main(const _Float16* __restrict__ xq,
                                                    const float* __restrict__ bias,
                                                    const float* __restrict__ wsf,
                                                    float* __restrict__ out) {
    // xs: 6 rows (h0-1..h0+4) x 130 j (w=j-1; j=0,129 = zero halo) x c8
    __shared__ __align__(16) _Float16 xs[2][6 * 130 * 8];    // 12480 B each
    __shared__ __align__(16) _Float16 wl[2][9 * 128 * 8];    // 18432 B each  (61824 total)

    float xmax = __uint_as_float(((const unsigned int*)wsf)[0]);
    float fx = xmax > 0.f ? FX_NUM / xmax : 1.0f;

    int bx = blockIdx.x;            // 1024 = 2 oh * 32 hq * 16 n
    int oh = bx & 1;
    int h0 = ((bx >> 1) & 31) << 2;
    int n  = bx >> 6;
    int o0 = oh << 7;

    int tid = threadIdx.x;
    int lane = tid & 63;
    int wv = tid >> 6;              // wave's output row = h0 + wv
    int m32 = lane & 31;
    int q2 = lane >> 5;

    const char* wqb = (const char*)wsf + WQB_OFF;
    const char* xbase_g = (const char*)xq + ((size_t)n * 16) * 128 * 2048;

    // zero both xs buffers (halo + invalid-row defaults persist: async never writes them)
    {
        uint4 z = {0u, 0u, 0u, 0u};
        uint4* p = (uint4*)xs;
        #pragma unroll 2
        for (int i = tid; i < (int)(sizeof(xs) / 16); i += 256) p[i] = z;
    }
    __syncthreads();

    floatx16 acc[4][4];
    #pragma unroll
    for (int a1 = 0; a1 < 4; a1++)
        #pragma unroll
        for (int a2 = 0; a2 < 4; a2++)
            #pragma unroll
            for (int e = 0; e < 16; e++) acc[a1][a2][e] = 0.f;

    auto stage_async = [&](int ci, int tb) {
        // 12 x-segs (6 rows x 2 KB) + 18 w-segs (18 KB), 1 KB per wave-inst
        const char* xci = xbase_g + (size_t)ci * 128 * 2048;
        for (int s = wv; s < 30; s += 4) {
            if (s < 12) {
                int r = s >> 1, seg = s & 1;
                int h = h0 + r - 1;
                if (h >= 0 && h < 128) {
                    const char* src = xci + (size_t)h * 2048 + seg * 1024 + (size_t)lane * 16;
                    char* dst = (char*)&xs[tb][(r * 130 + 1) * 8] + seg * 1024;
                    gl_lds16(src, dst);
                }
            } else {
                int t2 = s - 12;    // 0..17
                const char* src = wqb + ((size_t)ci * 2 + oh) * 18432 + t2 * 1024 + (size_t)lane * 16;
                char* dst = (char*)&wl[tb][0] + t2 * 1024;
                gl_lds16(src, dst);
            }
        }
    };

    stage_async(0, 0);
    __syncthreads();                // vmcnt(0) drain: chunk 0 ready

    for (int ci = 0; ci < 16; ++ci) {
        int cb = ci & 1;
        if (ci < 15) stage_async(ci + 1, cb ^ 1);

        const _Float16* xb = &xs[cb][(wv * 130 + m32) * 8];
        const _Float16* wb = &wl[cb][m32 * 8];

        #pragma unroll
        for (int p = 0; p < 5; ++p) {
            const int t0 = 2 * p;
            const int t1 = (2 * p + 1 > 8) ? 8 : 2 * p + 1;
            const int x0 = ((t0 / 3) * 130 + (t0 % 3)) * 8;
            const int x1 = ((t1 / 3) * 130 + (t1 % 3)) * 8;
            const int w0o = t0 * 1024;       // tap * 128 * 8 halves
            const int w1o = t1 * 1024;
            int xoff = q2 ? x1 : x0;
            int woff = q2 ? w1o : w0o;

            half8 af[4], bf[4];
            #pragma unroll
            for (int ot = 0; ot < 4; ++ot) af[ot] = *(const half8*)(wb + woff + ot * 256);
            if (p == 4) {                    // tap8 pairs with nothing: zero A on q2 lanes
                half8 zz = {};
                if (q2) {
                    #pragma unroll
                    for (int ot = 0; ot < 4; ++ot) af[ot] = zz;
                }
            }
            #pragma unroll
            for (int pt = 0; pt < 4; ++pt) bf[pt] = *(const half8*)(xb + xoff + pt * 256);

            #pragma unroll
            for (int ot = 0; ot < 4; ++ot)
                #pragma unroll
                for (int pt = 0; pt < 4; ++pt)
                    acc[ot][pt] = __builtin_amdgcn_mfma_f32_32x32x16_f16(af[ot], bf[pt], acc[ot][pt], 0, 0, 0);
        }
        __syncthreads();            // drains next chunk's asyncs; frees cb for ci+2
    }

    // epilogue: D row = o (reg), col = pixel (lane)
    int h = h0 + wv;
    #pragma unroll
    for (int ot = 0; ot < 4; ++ot) {
        #pragma unroll
        for (int e = 0; e < 16; ++e) {
            int o_loc = ot * 32 + (e & 3) + 8 * (e >> 2) + 4 * q2;
            int o = o0 + o_loc;
            float scale = 1.0f / (fx * wsf[64 + o]);
            float bv = bias[o];
            float* op = out + (((size_t)(n * 256 + o)) * 128 + h) * 128 + m32;
            #pragma unroll
            for (int pt = 0; pt < 4; ++pt)
                op[pt * 32] = fmaxf(fmaf(acc[ot][pt][e], scale, bv), 0.f);
        }
    }
}

// ---------------- fallback (R2 kernel, used if ws too small) ----------------
__global__ __launch_bounds__(256, 2) void conv_fallback(const float* __restrict__ x,
                                                        const float* __restrict__ bias,
                                                        const float* __restrict__ wsf,
                                                        float* __restrict__ out) {
    __shared__ __align__(16) _Float16 xsf[6 * JW * CKP];
    __shared__ __align__(16) _Float16 wlds[9 * 64 * CKP];

    const unsigned int* wsu = (const unsigned int*)wsf;
    float xmax = __uint_as_float(wsu[0]);
    float fx = xmax > 0.f ? FX_NUM / xmax : 1.0f;

    int bx = blockIdx.x;
    int n  = bx >> 5;
    int h0 = (bx & 31) << 2;
    int o0 = blockIdx.y << 6;

    int tid  = threadIdx.x;
    int lane = tid & 63;
    int wave = tid >> 6;
    int m32  = lane & 31;
    int q2   = lane >> 5;

    const _Float16* wq16 = (const _Float16*)((const char*)wsf + WQA_OFF);
    const float* xn = x + (size_t)n * (128 * 128 * 128);

    floatx16 acc[4][2];
    #pragma unroll
    for (int mt = 0; mt < 4; mt++)
        #pragma unroll
        for (int nt = 0; nt < 2; nt++)
            #pragma unroll
            for (int e = 0; e < 16; e++) acc[mt][nt][e] = 0.f;

    if (tid < 192) {
        int r = tid >> 5;
        int s = tid & 31;
        int c = s & 15;
        int j = (s >> 4) ? (JW - 1) : 0;
        xsf[(r * JW + j) * CKP + c] = (_Float16)0.f;
    }

    for (int c0 = 0; c0 < 128; c0 += CK) {
        __syncthreads();
        #pragma unroll
        for (int it = 0; it < 12; ++it) {
            int idx = tid + it * 256;
            int j  = (idx & 127) + 1;
            int c4 = (idx >> 7) & 3;
            int r  = idx >> 9;
            int h  = h0 + r - 1;
            float v0 = 0.f, v1 = 0.f, v2 = 0.f, v3 = 0.f;
            if (h >= 0 && h < 128) {
                const float* xp = xn + (size_t)(c0 + c4 * 4) * 16384 + h * 128 + (j - 1);
                v0 = xp[0]; v1 = xp[16384]; v2 = xp[32768]; v3 = xp[49152];
            }
            half4 hv;
            hv[0] = (_Float16)rintf(fx * v0);
            hv[1] = (_Float16)rintf(fx * v1);
            hv[2] = (_Float16)rintf(fx * v2);
            hv[3] = (_Float16)rintf(fx * v3);
            *(half4*)&xsf[(r * JW + j) * CKP + c4 * 4] = hv;
        }
        #pragma unroll
        for (int it = 0; it < 5; ++it) {
            int idx = tid + it * 256;
            if (idx < 1152) {
                int o   = idx / 18;
                int rem = idx - o * 18;
                int tap = rem >> 1;
                int g   = rem & 1;
                half8 v = *(const half8*)(wq16 + ((size_t)(o0 + o) * 9 + tap) * 128 + c0 + g * 8);
                *(half8*)&wlds[(tap * 64 + o) * CKP + g * 8] = v;
            }
        }
        __syncthreads();

        const _Float16* xbase = &xsf[(wave * JW + m32) * CKP + q2 * 8];
        const _Float16* wbase = &wlds[m32 * CKP + q2 * 8];
        #pragma unroll
        for (int kh = 0; kh < 3; ++kh) {
            #pragma unroll
            for (int kw = 0; kw < 3; ++kw) {
                int tap = kh * 3 + kw;
                half8 b0 = *(const half8*)(wbase + (tap * 64 +  0) * CKP);
                half8 b1 = *(const half8*)(wbase + (tap * 64 + 32) * CKP);
                #pragma unroll
                for (int mt = 0; mt < 4; ++mt) {
                    half8 a = *(const half8*)(xbase + (kh * JW + kw + mt * 32) * CKP);
                    acc[mt][0] = __builtin_amdgcn_mfma_f32_32x32x16_f16(a, b0, acc[mt][0], 0, 0, 0);
                    acc[mt][1] = __builtin_amdgcn_mfma_f32_32x32x16_f16(a, b1, acc[mt][1], 0, 0, 0);
                }
            }
        }
    }

    int h = h0 + wave;
    #pragma unroll
    for (int nt = 0; nt < 2; ++nt) {
        int o = o0 + nt * 32 + m32;
        float fwv = wsf[64 + o];
        float scale = 1.0f / (fx * fwv);
        float bv = bias[o];
        float* op = out + (((size_t)n * 256 + o) * 128 + h) * 128;
        #pragma unroll
        for (int mt = 0; mt < 4; ++mt) {
            #pragma unroll
            for (int g = 0; g < 4; ++g) {
                int w = mt * 32 + 8 * g + 4 * q2;
                float4 r;
                r.x = fmaxf(fmaf(acc[mt][nt][4 * g + 0], scale, bv), 0.f);
                r.y = fmaxf(fmaf(acc[mt][nt][4 * g + 1], scale, bv), 0.f);
                r.z = fmaxf(fmaf(acc[mt][nt][4 * g + 2], scale, bv), 0.f);
                r.w = fmaxf(fmaf(acc[mt][nt][4 * g + 3], scale, bv), 0.f);
                *(float4*)(op + w) = r;
            }
        }
    }
}

extern "C" void kernel_launch(void* const* d_in, const int* in_sizes, int n_in,
                              void* d_out, int out_size, void* d_ws, size_t ws_size,
                              hipStream_t stream) {
    const float* x = (const float*)d_in[0];   // [16,128,128,128]
    const float* W = (const float*)d_in[1];   // [256,128,3,3]
    const float* b = (const float*)d_in[2];   // [256]
    float* out = (float*)d_out;
    float* wsf = (float*)d_ws;

    int big = (ws_size >= (size_t)XQ_OFF + XQ_BYTES) ? 1 : 0;

    hipMemsetAsync(d_ws, 0, 256, stream);     // xmax slot (ws poisoned 0xAA)

    xmax_kernel<<<1024, 256, 0, stream>>>(x, (unsigned int*)d_ws, (16 * 128 * 128 * 128) / 4);
    wq_kernel<<<256, 128, 0, stream>>>(W, wsf, big);

    if (big) {
        _Float16* xq = (_Float16*)((char*)d_ws + XQ_OFF);
        quantx_kernel<<<16 * 16 * 128, 128, 0, stream>>>(x, wsf, xq);
        conv_main<<<1024, 256, 0, stream>>>(xq, b, wsf, out);
    } else {
        dim3 grid(512, 4);
        conv_fallback<<<grid, 4 * 64, 0, stream>>>(x, b, wsf, out);
    }
}